// Round 1
// baseline (362.531 us; speedup 1.0000x reference)
//
#include <hip/hip_runtime.h>
#include <hip/hip_bf16.h>
#include <cfloat>

// Problem constants (reference: B=4, L=4096, D=1024, H=16, Dh=64)
#define BB 4
#define LL 4096
#define DD 1024
#define HH 16
#define DHH 64
#define MM (BB * LL)          // 16384 rows
#define LN_EPS 1e-5f
#define LDQVG 3072            // fused q|v|g row stride
#define SCC 16                // scan chunk length
#define NCHUNK (LL / SCC)     // 256 chunks per batch

typedef __hip_bfloat16 bf16;
typedef __attribute__((ext_vector_type(8))) short short8;
typedef __attribute__((ext_vector_type(4))) float f32x4;

struct bf16x4 { bf16 a, b, c, d; };
struct alignas(16) bf8 { bf16 e[8]; };

__device__ __forceinline__ float b2f(bf16 u) {
    union { unsigned int i; float f; } c;
    c.i = ((unsigned int)__bfloat16_as_ushort(u)) << 16;
    return c.f;
}

__device__ __forceinline__ float lam_of(const float* beta, int head) {
    float lam = 1.0f - exp2f(-beta[head]);
    return fminf(fmaxf(lam, 1.1754944e-38f), 1.0f - 1e-9f);
}

// ---------------------------------------------------------------------------
// All f32->bf16 conversions in ONE dispatch: x (16384 blocks) then the four
// weight matrices (4*1024 blocks) into contiguous wq|wv|wg|wo.
// ---------------------------------------------------------------------------
__global__ __launch_bounds__(256) void cvt_all(const float* __restrict__ x,
                                               const float* __restrict__ wq,
                                               const float* __restrict__ wv,
                                               const float* __restrict__ wg,
                                               const float* __restrict__ wo,
                                               bf16* __restrict__ xb,
                                               bf16* __restrict__ wb) {
    const int blk = blockIdx.x;
    const float* src;
    bf16* dst;
    size_t off;
    if (blk < 16384) {
        src = x; dst = xb; off = (size_t)blk * 1024;
    } else {
        int wblk  = blk - 16384;
        int which = wblk >> 10;
        src = (which == 0) ? wq : (which == 1) ? wv : (which == 2) ? wg : wo;
        dst = wb + (size_t)which * 1048576;
        off = (size_t)(wblk & 1023) * 1024;
    }
    size_t i = off + threadIdx.x * 4;
    float4 f = *(const float4*)(src + i);
    bf16x4 o;
    o.a = __float2bfloat16(f.x);
    o.b = __float2bfloat16(f.y);
    o.c = __float2bfloat16(f.z);
    o.d = __float2bfloat16(f.w);
    *(bf16x4*)(dst + i) = o;
}

// ---------------------------------------------------------------------------
// async 16B global -> LDS. NOTE: imm offset applies to BOTH global and LDS
// addresses (R4 failure) — always pass 0, advance global pointers manually.
// ---------------------------------------------------------------------------
__device__ __forceinline__ void async16(const bf16* g, bf16* l) {
    __builtin_amdgcn_global_load_lds(
        (const __attribute__((address_space(1))) void*)g,
        (__attribute__((address_space(3))) void*)l,
        16, 0, 0);
}

// ---------------------------------------------------------------------------
// GEMM: C[M,N] = A[M,K] * B[N,K]^T  (row-major, K contiguous), ldc row stride.
// 256x256 tile, 512 threads = 8 waves (2M x 4N), per-wave 128x64 output via
// mfma_f32_16x16x32_bf16 (acc[8][4] of f32x4 = 128 VGPR).
//
// 8-phase-equivalent schedule (T2+T3+T4+T5 per the catalog):
//  - LDS: ring-4 of 16KiB slots per matrix (BK=32) = 128 KiB total.
//  - while computing tile T (2 phases, 16 MFMA each) we stage tile T+3 via
//    global_load_lds (2 loads/phase/thread) -> 2.5 tiles in flight.
//  - end-of-tile wait is counted vmcnt(8) (retires T+1, leaves T+2/T+3 in
//    flight); epilogue drains 8->4->0. Never vmcnt(0) in steady state.
//  - raw s_barrier (no __syncthreads vmcnt-drain); setprio(1) around MFMA.
//  - LDS swizzle: phys k-chunk = logical ^ (row&3), applied as pre-swizzled
//    GLOBAL source + linear LDS dest (rule #21), and on the ds_read address.
//    With 16-row fragments this makes ds_read_b128 2 lanes/bank (free).
// Slot-overwrite safety: stage of tile T+3 targets slot (T-1)&3, whose last
// ds_read was in the previous phase, completed (lgkmcnt) before the barrier
// the staging wave crossed. Stage completion before read: prior tile's
// vmcnt(8) guarantees tile T retired before any wave reads slot T&3.
// ---------------------------------------------------------------------------
template <typename OutT, int KK>
__global__ __launch_bounds__(512, 2) void gemm256(const bf16* __restrict__ A,
                                                  const bf16* __restrict__ Bm,
                                                  OutT* __restrict__ C,
                                                  int ldc) {
    constexpr int BK   = 32;
    constexpr int NT   = KK / BK;        // 32 tiles
    constexpr int SLOT = 256 * BK;       // 8192 bf16 elements = 16 KiB

    __shared__ alignas(16) bf16 sA[4 * SLOT];   // 64 KiB
    __shared__ alignas(16) bf16 sB[4 * SLOT];   // 64 KiB

    const int t    = threadIdx.x;
    const int lane = t & 63;
    const int wave = t >> 6;
    const int wm   = wave >> 2;          // 0..1  (M half)
    const int wn   = wave & 3;           // 0..3  (N quarter)
    const int bm   = blockIdx.x;
    const int bn   = blockIdx.y;

    // ---- staging addressing: pre-swizzled global source, linear LDS dest.
    // thread t covers row srow (64B/row, 4 chunks of 16B), phys chunk t&3,
    // which must hold logical chunk (t&3) ^ (srow&3).
    const int srow = t >> 2;                           // 0..127 within unit
    const int cswz = ((t & 3) ^ (srow & 3)) * 8;       // element offset in BK
    const bf16* gA0 = A  + (size_t)(bm * 256 + srow) * KK + cswz;
    const bf16* gB0 = Bm + (size_t)(bn * 256 + srow) * KK + cswz;
    const size_t half = (size_t)128 * KK;              // +128 rows (same swz: 128%4==0)
    bf16* const lA = sA + t * 8;
    bf16* const lB = sB + t * 8;

    // ---- ds_read addressing: lane l reads row (frag*16 + (l&15)),
    // logical chunk (l>>4), phys = (l>>4) ^ (row&3) = (l>>4) ^ (l&3).
    const int swz8  = ((lane >> 4) ^ (lane & 3)) * 8;
    const int offA0 = (wm * 128 + (lane & 15)) * BK + swz8;   // +mi*512
    const int offB0 = (wn * 64  + (lane & 15)) * BK + swz8;   // +ni*512

    f32x4 acc[8][4] = {};

#define STAGE_A(Tn) { const int sl = ((Tn) & 3) * SLOT;                  \
    const bf16* g = gA0 + (Tn) * BK;                                     \
    async16(g, lA + sl); async16(g + half, lA + sl + 4096); }
#define STAGE_B(Tn) { const int sl = ((Tn) & 3) * SLOT;                  \
    const bf16* g = gB0 + (Tn) * BK;                                     \
    async16(g, lB + sl); async16(g + half, lB + sl + 4096); }

    // prologue: tiles 0,1,2 issued (12 loads); tile 0 retired at vmcnt(8).
    STAGE_A(0); STAGE_B(0);
    STAGE_A(1); STAGE_B(1);
    STAGE_A(2); STAGE_B(2);
    asm volatile("s_waitcnt vmcnt(8)" ::: "memory");
    __builtin_amdgcn_s_barrier();

#define TILE(T, DOSTAGE, VMN)                                                  \
  {                                                                            \
    const bf16* sbA = sA + ((T) & 3) * SLOT;                                   \
    const bf16* sbB = sB + ((T) & 3) * SLOT;                                   \
    short8 av[4], bv[4];                                                       \
    _Pragma("unroll") for (int i = 0; i < 4; ++i)                              \
        av[i] = *(const short8*)(sbA + offA0 + i * 512);                       \
    _Pragma("unroll") for (int i = 0; i < 4; ++i)                              \
        bv[i] = *(const short8*)(sbB + offB0 + i * 512);                       \
    if (DOSTAGE) STAGE_A((T) + 3);                                             \
    __builtin_amdgcn_s_barrier();                                              \
    __builtin_amdgcn_s_setprio(1);                                             \
    _Pragma("unroll") for (int i = 0; i < 4; ++i)                              \
      _Pragma("unroll") for (int j = 0; j < 4; ++j)                            \
        acc[i][j] = __builtin_amdgcn_mfma_f32_16x16x32_bf16(                   \
            av[i], bv[j], acc[i][j], 0, 0, 0);                                 \
    __builtin_amdgcn_s_setprio(0);                                             \
    __builtin_amdgcn_s_barrier();                                              \
    _Pragma("unroll") for (int i = 0; i < 4; ++i)                              \
        av[i] = *(const short8*)(sbA + offA0 + (4 + i) * 512);                 \
    if (DOSTAGE) STAGE_B((T) + 3);                                             \
    __builtin_amdgcn_s_barrier();                                              \
    __builtin_amdgcn_s_setprio(1);                                             \
    _Pragma("unroll") for (int i = 0; i < 4; ++i)                              \
      _Pragma("unroll") for (int j = 0; j < 4; ++j)                            \
        acc[4 + i][j] = __builtin_amdgcn_mfma_f32_16x16x32_bf16(               \
            av[i], bv[j], acc[4 + i][j], 0, 0, 0);                             \
    __builtin_amdgcn_s_setprio(0);                                             \
    if ((VMN) == 8)      asm volatile("s_waitcnt vmcnt(8)" ::: "memory");      \
    else if ((VMN) == 4) asm volatile("s_waitcnt vmcnt(4)" ::: "memory");      \
    else if ((VMN) == 0) asm volatile("s_waitcnt vmcnt(0)" ::: "memory");      \
    __builtin_amdgcn_s_barrier();                                              \
  }

#pragma unroll 1
    for (int T = 0; T < NT - 3; ++T) {
        TILE(T, true, 8);
    }
    TILE(NT - 3, false, 4);
    TILE(NT - 2, false, 0);
    TILE(NT - 1, false, -1);

#undef TILE
#undef STAGE_A
#undef STAGE_B

    // epilogue: C/D layout (16x16): col = lane&15, row = (lane>>4)*4 + reg
    const int col0 = bn * 256 + wn * 64 + (lane & 15);
    const int row0 = bm * 256 + wm * 128 + ((lane >> 4) * 4);
#pragma unroll
    for (int mi = 0; mi < 8; ++mi) {
#pragma unroll
        for (int ni = 0; ni < 4; ++ni) {
#pragma unroll
            for (int r = 0; r < 4; ++r) {
                int row = row0 + mi * 16 + r;
                C[(size_t)row * ldc + col0 + ni * 16] = (OutT)acc[mi][ni][r];
            }
        }
    }
}

// ---------------------------------------------------------------------------
// Exact two-phase retention scan over fused qvg layout (row stride 3072).
// Phase A: per-chunk local scan -> chunk sums S.
// Phase B: carry scan over chunks (8-wide prefetch pipeline).
// Phase C (fused with LN+gate below): re-scan from carry, LN, gate, write z.
// ---------------------------------------------------------------------------
__global__ __launch_bounds__(64) void scan_chunksum(const bf16* __restrict__ qvg,
                                                    const float* __restrict__ beta,
                                                    float* __restrict__ S) {
    const int c    = blockIdx.x;
    const int half = blockIdx.y;
    const int b    = blockIdx.z;
    const int tid  = threadIdx.x;
    const int dh0  = half * 512 + tid * 8;
    const float lam = lam_of(beta, dh0 >> 6);

    const bf16* vp = qvg + 1024 + ((size_t)(b * LL + c * SCC)) * LDQVG + dh0;

    float s[8] = {};
#pragma unroll
    for (int t = 0; t < SCC; ++t) {
        bf8 vv = *(const bf8*)(vp + (size_t)t * LDQVG);
#pragma unroll
        for (int j = 0; j < 8; ++j)
            s[j] = fmaf(s[j], lam, b2f(vv.e[j]));
    }

    float* sp = S + ((size_t)(b * NCHUNK + c)) * DD + dh0;
    float4 lo = {s[0], s[1], s[2], s[3]};
    float4 hi = {s[4], s[5], s[6], s[7]};
    *(float4*)(sp)     = lo;
    *(float4*)(sp + 4) = hi;
}

// Serial carry over 256 chunks, 8-wide load prefetch to break the
// latency chain (loads for batch i+1 are independent of the t-recurrence).
__global__ __launch_bounds__(64) void scan_carry(const float* __restrict__ S,
                                                 float* __restrict__ T,
                                                 const float* __restrict__ beta) {
    const int gid = blockIdx.x * 64 + threadIdx.x;  // 0..4095
    const int b = gid >> 10;
    const int f = gid & 1023;
    const float lam  = lam_of(beta, f >> 6);
    const float lamC = powf(lam, (float)SCC);

    const size_t base = (size_t)b * NCHUNK * DD + f;

    float v[8];
#pragma unroll
    for (int j = 0; j < 8; ++j) v[j] = S[base + (size_t)j * DD];

    float t = 0.0f;
    for (int c0 = 0; c0 < NCHUNK; c0 += 8) {
        float cur[8];
#pragma unroll
        for (int j = 0; j < 8; ++j) cur[j] = v[j];
        if (c0 + 8 < NCHUNK) {
#pragma unroll
            for (int j = 0; j < 8; ++j)
                v[j] = S[base + (size_t)(c0 + 8 + j) * DD];
        }
#pragma unroll
        for (int j = 0; j < 8; ++j) {
            T[base + (size_t)(c0 + j) * DD] = t;
            t = fmaf(t, lamC, cur[j]);
        }
    }
}

// ---------------------------------------------------------------------------
// Fused: re-scan chunk from carry T -> ret (kept in LDS), per-row LayerNorm,
// SiLU gate, write z (bf16, contiguous [M,1024]). ret never touches HBM.
// grid (NCHUNK, BB), 128 threads (2 waves). LDS 16 rows x 1024 bf16 = 32KB.
// ---------------------------------------------------------------------------
__global__ __launch_bounds__(128) void scan_apply_ln(const bf16* __restrict__ qvg,
                                                     const float* __restrict__ beta,
                                                     const float* __restrict__ T,
                                                     const float* __restrict__ gamma,
                                                     const float* __restrict__ betaln,
                                                     bf16* __restrict__ z) {
    __shared__ bf16 lds_ret[SCC][DD];   // 32 KB

    const int c   = blockIdx.x;
    const int b   = blockIdx.y;
    const int tid = threadIdx.x;        // 0..127
    const int f0  = tid * 8;
    const float lam = lam_of(beta, f0 >> 6);

    // ---- phase 1: local scan from carry, ret -> LDS ----
    const float* tp = T + ((size_t)(b * NCHUNK + c)) * DD + f0;
    float4 lo = *(const float4*)(tp);
    float4 hi = *(const float4*)(tp + 4);
    float s[8] = {lo.x, lo.y, lo.z, lo.w, hi.x, hi.y, hi.z, hi.w};

    const bf16* qp = qvg + ((size_t)(b * LL + c * SCC)) * LDQVG + f0;
#pragma unroll
    for (int t = 0; t < SCC; ++t) {
        const size_t off = (size_t)t * LDQVG;
        bf8 vv = *(const bf8*)(qp + 1024 + off);
        bf8 qq = *(const bf8*)(qp + off);
        bf8 o;
#pragma unroll
        for (int j = 0; j < 8; ++j) {
            s[j] = fmaf(s[j], lam, b2f(vv.e[j]));
            o.e[j] = __float2bfloat16(b2f(qq.e[j]) * s[j]);
        }
        *(bf8*)(&lds_ret[t][f0]) = o;
    }
    __syncthreads();

    // ---- phase 2: per-row LN + SiLU gate. wave w does rows w, w+2, ... ----
    const int lane = tid & 63;
    const int wv   = tid >> 6;

    // cache gamma/beta for this lane's two feature groups (lane*8, 512+lane*8)
    float gmA[8], btA[8], gmB[8], btB[8];
#pragma unroll
    for (int j = 0; j < 8; j += 4) {
        *(float4*)(gmA + j) = *(const float4*)(gamma  + lane * 8 + j);
        *(float4*)(btA + j) = *(const float4*)(betaln + lane * 8 + j);
        *(float4*)(gmB + j) = *(const float4*)(gamma  + 512 + lane * 8 + j);
        *(float4*)(btB + j) = *(const float4*)(betaln + 512 + lane * 8 + j);
    }

    for (int t = wv; t < SCC; t += 2) {
        bf8 rA = *(const bf8*)(&lds_ret[t][lane * 8]);
        bf8 rB = *(const bf8*)(&lds_ret[t][512 + lane * 8]);

        float xa[8], xb2[8];
        float sum = 0.f, sq = 0.f;
#pragma unroll
        for (int j = 0; j < 8; ++j) {
            xa[j]  = b2f(rA.e[j]);
            xb2[j] = b2f(rB.e[j]);
            sum += xa[j] + xb2[j];
            sq  += xa[j] * xa[j] + xb2[j] * xb2[j];
        }
#pragma unroll
        for (int off = 32; off >= 1; off >>= 1) {
            sum += __shfl_xor(sum, off, 64);
            sq  += __shfl_xor(sq,  off, 64);
        }
        const float mu   = sum * (1.0f / DD);
        const float var  = sq * (1.0f / DD) - mu * mu;
        const float rstd = rsqrtf(var + LN_EPS);

        const size_t row = (size_t)(b * LL + c * SCC + t);
        const bf16* gp = qvg + row * LDQVG + 2048 + lane * 8;
        bf8 gA = *(const bf8*)(gp);
        bf8 gB = *(const bf8*)(gp + 512);

        bf8 oA, oB;
#pragma unroll
        for (int j = 0; j < 8; ++j) {
            float ya = (xa[j]  - mu) * rstd * gmA[j] + btA[j];
            float yb = (xb2[j] - mu) * rstd * gmB[j] + btB[j];
            float ga = b2f(gA.e[j]);
            float gb = b2f(gB.e[j]);
            oA.e[j] = __float2bfloat16(ya * (ga / (1.0f + expf(-ga))));
            oB.e[j] = __float2bfloat16(yb * (gb / (1.0f + expf(-gb))));
        }
        bf16* zp = z + row * DD + lane * 8;
        *(bf8*)(zp)       = oA;
        *(bf8*)(zp + 512) = oB;
    }
}

// ---------------------------------------------------------------------------
// launch
// ---------------------------------------------------------------------------
extern "C" void kernel_launch(void* const* d_in, const int* in_sizes, int n_in,
                              void* d_out, int out_size, void* d_ws, size_t ws_size,
                              hipStream_t stream) {
    const float* x     = (const float*)d_in[0];
    const float* Wq    = (const float*)d_in[1];
    const float* Wv    = (const float*)d_in[2];
    const float* Wo    = (const float*)d_in[3];
    const float* Wg    = (const float*)d_in[4];
    const float* beta  = (const float*)d_in[5];
    const float* ln_g  = (const float*)d_in[6];
    const float* ln_b  = (const float*)d_in[7];
    float* out = (float*)d_out;

    char* ws = (char*)d_ws;
    // workspace (136MB total, time-multiplexed):
    //   @0    : xb 32MB (cvt -> QVG GEMM)  ->  S 4MB (chunksum -> carry)
    //           -> zb 32MB (apply_ln -> final GEMM)
    //   @32MB : wqb 6MB (wq|wv|wg; dead after QVG GEMM) -> T 4MB (carry -> apply)
    //   @38MB : wob 2MB (live until final GEMM)
    //   @40MB : qvg 96MB [M,3072] = q|v|g per row
    bf16*  xb   = (bf16*)ws;
    float* Sbuf = (float*)ws;                                  // alias xb (dead)
    bf16*  wqb  = (bf16*)(ws + (size_t)32 * 1024 * 1024);
    float* Tbuf = (float*)(ws + (size_t)32 * 1024 * 1024);     // alias wqb (dead)
    bf16*  wob  = wqb + 3 * 1048576;
    bf16*  qvg  = (bf16*)(ws + (size_t)40 * 1024 * 1024);
    bf16*  zb   = xb;

    // all dtype conversions in one dispatch (x + 4 weights)
    cvt_all<<<dim3(16384 + 4096), dim3(256), 0, stream>>>(x, Wq, Wv, Wg, Wo, xb, wqb);

    // fused QVG GEMM: [M,1024] x [3072,1024]^T -> [M,3072]
    gemm256<bf16, DD><<<dim3(MM / 256, LDQVG / 256), dim3(512), 0, stream>>>(
        xb, wqb, qvg, LDQVG);

    // exact two-phase retention scan + fused LN/gate
    scan_chunksum<<<dim3(NCHUNK, 2, BB), dim3(64), 0, stream>>>(qvg, beta, Sbuf);
    scan_carry<<<dim3(64), dim3(64), 0, stream>>>(Sbuf, Tbuf, beta);
    scan_apply_ln<<<dim3(NCHUNK, BB), dim3(128), 0, stream>>>(
        qvg, beta, Tbuf, ln_g, ln_b, zb);

    // final GEMM: [M,1024] x [1024,1024]^T -> [M,1024] f32
    gemm256<float, DD><<<dim3(MM / 256, DD / 256), dim3(512), 0, stream>>>(
        zb, wob, out, DD);
}

// Round 2
// 356.284 us; speedup vs baseline: 1.0175x; 1.0175x over previous
//
#include <hip/hip_runtime.h>
#include <hip/hip_bf16.h>
#include <cfloat>

// Problem constants (reference: B=4, L=4096, D=1024, H=16, Dh=64)
#define BB 4
#define LL 4096
#define DD 1024
#define HH 16
#define DHH 64
#define MM (BB * LL)          // 16384 rows
#define LN_EPS 1e-5f
#define LDQVG 3072            // fused q|v|g row stride
#define SCC 16                // scan chunk length
#define NCHUNK (LL / SCC)     // 256 chunks per batch

typedef __hip_bfloat16 bf16;
typedef __attribute__((ext_vector_type(8))) short short8;
typedef __attribute__((ext_vector_type(4))) float f32x4;

struct bf16x4 { bf16 a, b, c, d; };
struct alignas(16) bf8 { bf16 e[8]; };

__device__ __forceinline__ float b2f(bf16 u) {
    union { unsigned int i; float f; } c;
    c.i = ((unsigned int)__bfloat16_as_ushort(u)) << 16;
    return c.f;
}

__device__ __forceinline__ float lam_of(const float* beta, int head) {
    float lam = 1.0f - exp2f(-beta[head]);
    return fminf(fmaxf(lam, 1.1754944e-38f), 1.0f - 1e-9f);
}

// ---------------------------------------------------------------------------
// All f32->bf16 conversions in ONE dispatch: x (16384 blocks) then the four
// weight matrices (4*1024 blocks) into contiguous wq|wv|wg|wo.
// ---------------------------------------------------------------------------
__global__ __launch_bounds__(256) void cvt_all(const float* __restrict__ x,
                                               const float* __restrict__ wq,
                                               const float* __restrict__ wv,
                                               const float* __restrict__ wg,
                                               const float* __restrict__ wo,
                                               bf16* __restrict__ xb,
                                               bf16* __restrict__ wb) {
    const int blk = blockIdx.x;
    const float* src;
    bf16* dst;
    size_t off;
    if (blk < 16384) {
        src = x; dst = xb; off = (size_t)blk * 1024;
    } else {
        int wblk  = blk - 16384;
        int which = wblk >> 10;
        src = (which == 0) ? wq : (which == 1) ? wv : (which == 2) ? wg : wo;
        dst = wb + (size_t)which * 1048576;
        off = (size_t)(wblk & 1023) * 1024;
    }
    size_t i = off + threadIdx.x * 4;
    float4 f = *(const float4*)(src + i);
    bf16x4 o;
    o.a = __float2bfloat16(f.x);
    o.b = __float2bfloat16(f.y);
    o.c = __float2bfloat16(f.z);
    o.d = __float2bfloat16(f.w);
    *(bf16x4*)(dst + i) = o;
}

// ---------------------------------------------------------------------------
// async 16B global -> LDS. NOTE: imm offset applies to BOTH global and LDS
// addresses (R4 failure) — always pass 0, advance global pointers manually.
// ---------------------------------------------------------------------------
__device__ __forceinline__ void async16(const bf16* g, bf16* l) {
    __builtin_amdgcn_global_load_lds(
        (const __attribute__((address_space(1))) void*)g,
        (__attribute__((address_space(3))) void*)l,
        16, 0, 0);
}

// ---------------------------------------------------------------------------
// GEMM: C[M,N] = A[M,K] * B[N,K]^T  (row-major, K contiguous), ldc row stride.
// 256x256 tile, 512 threads = 8 waves (2M x 4N), per-wave 128x64 output via
// mfma_f32_16x16x32_bf16 (acc[8][4] of f32x4 = 128 acc regs).
//
// 8-phase-equivalent schedule (T2+T3+T4+T5 per the catalog):
//  - LDS: ring-4 of 16KiB slots per matrix (BK=32) = 128 KiB total.
//  - while computing tile T (2 phases, 16 MFMA each) we stage tile T+3 via
//    global_load_lds (2 loads/phase/thread) -> 2.5 tiles in flight.
//  - end-of-tile wait is counted vmcnt(8) (retires T+1, leaves T+2/T+3 in
//    flight); epilogue drains 8->4->0. Never vmcnt(0) in steady state.
//  - raw s_barrier (no __syncthreads vmcnt-drain); setprio(1) around MFMA.
//  - LDS swizzle (R1 fix): phys k-chunk = logical ^ ((row>>1)&3).
//    Bank math: a b128 from row r, phys chunk p hits 16B-slot (4r+p) mod 8;
//    4r mod 8 = 4*(r&1), so f(row) must cover 0..3 twice over even rows and
//    twice over odd rows -> f=(row>>1)&3. Full wave64: 8 lanes/slot exactly
//    (the 1024B/128B floor). R0's f=row&3 left a 4-on-half-slots imbalance
//    (9.4e6 SQ_LDS_BANK_CONFLICT, 2x LDS serialization).
//    Applied as pre-swizzled GLOBAL source + linear LDS dest (rule #21) and
//    the same XOR on the ds_read address.
// Slot-overwrite safety: stage of tile T+3 targets slot (T-1)&3, whose last
// ds_read was in the previous tile, completed (lgkmcnt) before the barrier
// the staging wave crossed. Stage completion before read: prior tile's
// vmcnt(8) + barrier guarantees tile T's loads (all waves) retired before
// any wave reads slot T&3.
// ---------------------------------------------------------------------------
template <typename OutT, int KK>
__global__ __launch_bounds__(512, 2) void gemm256(const bf16* __restrict__ A,
                                                  const bf16* __restrict__ Bm,
                                                  OutT* __restrict__ C,
                                                  int ldc) {
    constexpr int BK   = 32;
    constexpr int NT   = KK / BK;        // 32 tiles
    constexpr int SLOT = 256 * BK;       // 8192 bf16 elements = 16 KiB

    __shared__ alignas(16) bf16 sA[4 * SLOT];   // 64 KiB
    __shared__ alignas(16) bf16 sB[4 * SLOT];   // 64 KiB

    const int t    = threadIdx.x;
    const int lane = t & 63;
    const int wave = t >> 6;
    const int wm   = wave >> 2;          // 0..1  (M half)
    const int wn   = wave & 3;           // 0..3  (N quarter)
    const int bm   = blockIdx.x;
    const int bn   = blockIdx.y;

    // ---- staging addressing: pre-swizzled global source, linear LDS dest.
    // thread t writes LDS bytes [t*16, t*16+16) = row srow=t>>2, phys chunk
    // t&3, which must hold logical chunk (t&3) ^ ((srow>>1)&3).
    const int srow = t >> 2;                                 // 0..127
    const int cswz = ((t & 3) ^ ((srow >> 1) & 3)) * 8;      // elem offset in BK
    const bf16* gA0 = A  + (size_t)(bm * 256 + srow) * KK + cswz;
    const bf16* gB0 = Bm + (size_t)(bn * 256 + srow) * KK + cswz;
    const size_t half = (size_t)128 * KK;  // +128 rows: (row+128)>>1 & 3 same
    bf16* const lA = sA + t * 8;
    bf16* const lB = sB + t * 8;

    // ---- ds_read addressing: lane l reads row base + (l&15), logical chunk
    // (l>>4), phys = (l>>4) ^ ((row>>1)&3); row base is a multiple of 16 so
    // (row>>1)&3 = ((l&15)>>1)&3, uniform across mi/ni.
    const int swz8  = ((lane >> 4) ^ (((lane & 15) >> 1) & 3)) * 8;
    const int offA0 = (wm * 128 + (lane & 15)) * BK + swz8;   // +mi*512
    const int offB0 = (wn * 64  + (lane & 15)) * BK + swz8;   // +ni*512

    f32x4 acc[8][4] = {};

#define STAGE_A(Tn) { const int sl = ((Tn) & 3) * SLOT;                  \
    const bf16* g = gA0 + (Tn) * BK;                                     \
    async16(g, lA + sl); async16(g + half, lA + sl + 4096); }
#define STAGE_B(Tn) { const int sl = ((Tn) & 3) * SLOT;                  \
    const bf16* g = gB0 + (Tn) * BK;                                     \
    async16(g, lB + sl); async16(g + half, lB + sl + 4096); }

    // prologue: tiles 0,1,2 issued (12 loads); tile 0 retired at vmcnt(8).
    STAGE_A(0); STAGE_B(0);
    STAGE_A(1); STAGE_B(1);
    STAGE_A(2); STAGE_B(2);
    asm volatile("s_waitcnt vmcnt(8)" ::: "memory");
    __builtin_amdgcn_s_barrier();

#define TILE(T, DOSTAGE, VMN)                                                  \
  {                                                                            \
    const bf16* sbA = sA + ((T) & 3) * SLOT;                                   \
    const bf16* sbB = sB + ((T) & 3) * SLOT;                                   \
    short8 av[4], bv[4];                                                       \
    _Pragma("unroll") for (int i = 0; i < 4; ++i)                              \
        av[i] = *(const short8*)(sbA + offA0 + i * 512);                       \
    _Pragma("unroll") for (int i = 0; i < 4; ++i)                              \
        bv[i] = *(const short8*)(sbB + offB0 + i * 512);                       \
    if (DOSTAGE) STAGE_A((T) + 3);                                             \
    __builtin_amdgcn_s_barrier();                                              \
    __builtin_amdgcn_s_setprio(1);                                             \
    _Pragma("unroll") for (int i = 0; i < 4; ++i)                              \
      _Pragma("unroll") for (int j = 0; j < 4; ++j)                            \
        acc[i][j] = __builtin_amdgcn_mfma_f32_16x16x32_bf16(                   \
            av[i], bv[j], acc[i][j], 0, 0, 0);                                 \
    __builtin_amdgcn_s_setprio(0);                                             \
    __builtin_amdgcn_s_barrier();                                              \
    _Pragma("unroll") for (int i = 0; i < 4; ++i)                              \
        av[i] = *(const short8*)(sbA + offA0 + (4 + i) * 512);                 \
    if (DOSTAGE) STAGE_B((T) + 3);                                             \
    __builtin_amdgcn_s_barrier();                                              \
    __builtin_amdgcn_s_setprio(1);                                             \
    _Pragma("unroll") for (int i = 0; i < 4; ++i)                              \
      _Pragma("unroll") for (int j = 0; j < 4; ++j)                            \
        acc[4 + i][j] = __builtin_amdgcn_mfma_f32_16x16x32_bf16(               \
            av[i], bv[j], acc[4 + i][j], 0, 0, 0);                             \
    __builtin_amdgcn_s_setprio(0);                                             \
    if ((VMN) == 8)      asm volatile("s_waitcnt vmcnt(8)" ::: "memory");      \
    else if ((VMN) == 4) asm volatile("s_waitcnt vmcnt(4)" ::: "memory");      \
    else if ((VMN) == 0) asm volatile("s_waitcnt vmcnt(0)" ::: "memory");      \
    __builtin_amdgcn_s_barrier();                                              \
  }

#pragma unroll 1
    for (int T = 0; T < NT - 3; ++T) {
        TILE(T, true, 8);
    }
    TILE(NT - 3, false, 4);
    TILE(NT - 2, false, 0);
    TILE(NT - 1, false, -1);

#undef TILE
#undef STAGE_A
#undef STAGE_B

    // epilogue: C/D layout (16x16): col = lane&15, row = (lane>>4)*4 + reg
    const int col0 = bn * 256 + wn * 64 + (lane & 15);
    const int row0 = bm * 256 + wm * 128 + ((lane >> 4) * 4);
#pragma unroll
    for (int mi = 0; mi < 8; ++mi) {
#pragma unroll
        for (int ni = 0; ni < 4; ++ni) {
#pragma unroll
            for (int r = 0; r < 4; ++r) {
                int row = row0 + mi * 16 + r;
                C[(size_t)row * ldc + col0 + ni * 16] = (OutT)acc[mi][ni][r];
            }
        }
    }
}

// ---------------------------------------------------------------------------
// Exact two-phase retention scan over fused qvg layout (row stride 3072).
// Phase A: per-chunk local scan -> chunk sums S.
// Phase B: carry scan over chunks (8-wide prefetch pipeline).
// Phase C (fused with LN+gate below): re-scan from carry, LN, gate, write z.
// ---------------------------------------------------------------------------
__global__ __launch_bounds__(64) void scan_chunksum(const bf16* __restrict__ qvg,
                                                    const float* __restrict__ beta,
                                                    float* __restrict__ S) {
    const int c    = blockIdx.x;
    const int half = blockIdx.y;
    const int b    = blockIdx.z;
    const int tid  = threadIdx.x;
    const int dh0  = half * 512 + tid * 8;
    const float lam = lam_of(beta, dh0 >> 6);

    const bf16* vp = qvg + 1024 + ((size_t)(b * LL + c * SCC)) * LDQVG + dh0;

    float s[8] = {};
#pragma unroll
    for (int t = 0; t < SCC; ++t) {
        bf8 vv = *(const bf8*)(vp + (size_t)t * LDQVG);
#pragma unroll
        for (int j = 0; j < 8; ++j)
            s[j] = fmaf(s[j], lam, b2f(vv.e[j]));
    }

    float* sp = S + ((size_t)(b * NCHUNK + c)) * DD + dh0;
    float4 lo = {s[0], s[1], s[2], s[3]};
    float4 hi = {s[4], s[5], s[6], s[7]};
    *(float4*)(sp)     = lo;
    *(float4*)(sp + 4) = hi;
}

// Serial carry over 256 chunks, 8-wide load prefetch to break the
// latency chain (loads for batch i+1 are independent of the t-recurrence).
__global__ __launch_bounds__(64) void scan_carry(const float* __restrict__ S,
                                                 float* __restrict__ T,
                                                 const float* __restrict__ beta) {
    const int gid = blockIdx.x * 64 + threadIdx.x;  // 0..4095
    const int b = gid >> 10;
    const int f = gid & 1023;
    const float lam  = lam_of(beta, f >> 6);
    const float lamC = powf(lam, (float)SCC);

    const size_t base = (size_t)b * NCHUNK * DD + f;

    float v[8];
#pragma unroll
    for (int j = 0; j < 8; ++j) v[j] = S[base + (size_t)j * DD];

    float t = 0.0f;
    for (int c0 = 0; c0 < NCHUNK; c0 += 8) {
        float cur[8];
#pragma unroll
        for (int j = 0; j < 8; ++j) cur[j] = v[j];
        if (c0 + 8 < NCHUNK) {
#pragma unroll
            for (int j = 0; j < 8; ++j)
                v[j] = S[base + (size_t)(c0 + 8 + j) * DD];
        }
#pragma unroll
        for (int j = 0; j < 8; ++j) {
            T[base + (size_t)(c0 + j) * DD] = t;
            t = fmaf(t, lamC, cur[j]);
        }
    }
}

// ---------------------------------------------------------------------------
// Fused: re-scan chunk from carry T -> ret (kept in LDS), per-row LayerNorm,
// SiLU gate, write z (bf16, contiguous [M,1024]). ret never touches HBM.
// grid (NCHUNK, BB), 128 threads (2 waves). LDS 16 rows x 1024 bf16 = 32KB.
// ---------------------------------------------------------------------------
__global__ __launch_bounds__(128) void scan_apply_ln(const bf16* __restrict__ qvg,
                                                     const float* __restrict__ beta,
                                                     const float* __restrict__ T,
                                                     const float* __restrict__ gamma,
                                                     const float* __restrict__ betaln,
                                                     bf16* __restrict__ z) {
    __shared__ bf16 lds_ret[SCC][DD];   // 32 KB

    const int c   = blockIdx.x;
    const int b   = blockIdx.y;
    const int tid = threadIdx.x;        // 0..127
    const int f0  = tid * 8;
    const float lam = lam_of(beta, f0 >> 6);

    // ---- phase 1: local scan from carry, ret -> LDS ----
    const float* tp = T + ((size_t)(b * NCHUNK + c)) * DD + f0;
    float4 lo = *(const float4*)(tp);
    float4 hi = *(const float4*)(tp + 4);
    float s[8] = {lo.x, lo.y, lo.z, lo.w, hi.x, hi.y, hi.z, hi.w};

    const bf16* qp = qvg + ((size_t)(b * LL + c * SCC)) * LDQVG + f0;
#pragma unroll
    for (int t = 0; t < SCC; ++t) {
        const size_t off = (size_t)t * LDQVG;
        bf8 vv = *(const bf8*)(qp + 1024 + off);
        bf8 qq = *(const bf8*)(qp + off);
        bf8 o;
#pragma unroll
        for (int j = 0; j < 8; ++j) {
            s[j] = fmaf(s[j], lam, b2f(vv.e[j]));
            o.e[j] = __float2bfloat16(b2f(qq.e[j]) * s[j]);
        }
        *(bf8*)(&lds_ret[t][f0]) = o;
    }
    __syncthreads();

    // ---- phase 2: per-row LN + SiLU gate. wave w does rows w, w+2, ... ----
    const int lane = tid & 63;
    const int wv   = tid >> 6;

    // cache gamma/beta for this lane's two feature groups (lane*8, 512+lane*8)
    float gmA[8], btA[8], gmB[8], btB[8];
#pragma unroll
    for (int j = 0; j < 8; j += 4) {
        *(float4*)(gmA + j) = *(const float4*)(gamma  + lane * 8 + j);
        *(float4*)(btA + j) = *(const float4*)(betaln + lane * 8 + j);
        *(float4*)(gmB + j) = *(const float4*)(gamma  + 512 + lane * 8 + j);
        *(float4*)(btB + j) = *(const float4*)(betaln + 512 + lane * 8 + j);
    }

    for (int t = wv; t < SCC; t += 2) {
        bf8 rA = *(const bf8*)(&lds_ret[t][lane * 8]);
        bf8 rB = *(const bf8*)(&lds_ret[t][512 + lane * 8]);

        float xa[8], xb2[8];
        float sum = 0.f, sq = 0.f;
#pragma unroll
        for (int j = 0; j < 8; ++j) {
            xa[j]  = b2f(rA.e[j]);
            xb2[j] = b2f(rB.e[j]);
            sum += xa[j] + xb2[j];
            sq  += xa[j] * xa[j] + xb2[j] * xb2[j];
        }
#pragma unroll
        for (int off = 32; off >= 1; off >>= 1) {
            sum += __shfl_xor(sum, off, 64);
            sq  += __shfl_xor(sq,  off, 64);
        }
        const float mu   = sum * (1.0f / DD);
        const float var  = sq * (1.0f / DD) - mu * mu;
        const float rstd = rsqrtf(var + LN_EPS);

        const size_t row = (size_t)(b * LL + c * SCC + t);
        const bf16* gp = qvg + row * LDQVG + 2048 + lane * 8;
        bf8 gA = *(const bf8*)(gp);
        bf8 gB = *(const bf8*)(gp + 512);

        bf8 oA, oB;
#pragma unroll
        for (int j = 0; j < 8; ++j) {
            float ya = (xa[j]  - mu) * rstd * gmA[j] + btA[j];
            float yb = (xb2[j] - mu) * rstd * gmB[j] + btB[j];
            float ga = b2f(gA.e[j]);
            float gb = b2f(gB.e[j]);
            oA.e[j] = __float2bfloat16(ya * (ga / (1.0f + expf(-ga))));
            oB.e[j] = __float2bfloat16(yb * (gb / (1.0f + expf(-gb))));
        }
        bf16* zp = z + row * DD + lane * 8;
        *(bf8*)(zp)       = oA;
        *(bf8*)(zp + 512) = oB;
    }
}

// ---------------------------------------------------------------------------
// launch
// ---------------------------------------------------------------------------
extern "C" void kernel_launch(void* const* d_in, const int* in_sizes, int n_in,
                              void* d_out, int out_size, void* d_ws, size_t ws_size,
                              hipStream_t stream) {
    const float* x     = (const float*)d_in[0];
    const float* Wq    = (const float*)d_in[1];
    const float* Wv    = (const float*)d_in[2];
    const float* Wo    = (const float*)d_in[3];
    const float* Wg    = (const float*)d_in[4];
    const float* beta  = (const float*)d_in[5];
    const float* ln_g  = (const float*)d_in[6];
    const float* ln_b  = (const float*)d_in[7];
    float* out = (float*)d_out;

    char* ws = (char*)d_ws;
    // workspace (136MB total, time-multiplexed):
    //   @0    : xb 32MB (cvt -> QVG GEMM)  ->  S 4MB (chunksum -> carry)
    //           -> zb 32MB (apply_ln -> final GEMM)
    //   @32MB : wqb 6MB (wq|wv|wg; dead after QVG GEMM) -> T 4MB (carry -> apply)
    //   @38MB : wob 2MB (live until final GEMM)
    //   @40MB : qvg 96MB [M,3072] = q|v|g per row
    bf16*  xb   = (bf16*)ws;
    float* Sbuf = (float*)ws;                                  // alias xb (dead)
    bf16*  wqb  = (bf16*)(ws + (size_t)32 * 1024 * 1024);
    float* Tbuf = (float*)(ws + (size_t)32 * 1024 * 1024);     // alias wqb (dead)
    bf16*  wob  = wqb + 3 * 1048576;
    bf16*  qvg  = (bf16*)(ws + (size_t)40 * 1024 * 1024);
    bf16*  zb   = xb;

    // all dtype conversions in one dispatch (x + 4 weights)
    cvt_all<<<dim3(16384 + 4096), dim3(256), 0, stream>>>(x, Wq, Wv, Wg, Wo, xb, wqb);

    // fused QVG GEMM: [M,1024] x [3072,1024]^T -> [M,3072]
    gemm256<bf16, DD><<<dim3(MM / 256, LDQVG / 256), dim3(512), 0, stream>>>(
        xb, wqb, qvg, LDQVG);

    // exact two-phase retention scan + fused LN/gate
    scan_chunksum<<<dim3(NCHUNK, 2, BB), dim3(64), 0, stream>>>(qvg, beta, Sbuf);
    scan_carry<<<dim3(64), dim3(64), 0, stream>>>(Sbuf, Tbuf, beta);
    scan_apply_ln<<<dim3(NCHUNK, BB), dim3(128), 0, stream>>>(
        qvg, beta, Tbuf, ln_g, ln_b, zb);

    // final GEMM: [M,1024] x [1024,1024]^T -> [M,1024] f32
    gemm256<float, DD><<<dim3(MM / 256, DD / 256), dim3(512), 0, stream>>>(
        zb, wob, out, DD);
}

// Round 3
// 348.392 us; speedup vs baseline: 1.0406x; 1.0227x over previous
//
#include <hip/hip_runtime.h>
#include <hip/hip_bf16.h>
#include <cfloat>

// Problem constants (reference: B=4, L=4096, D=1024, H=16, Dh=64)
#define BB 4
#define LL 4096
#define DD 1024
#define HH 16
#define DHH 64
#define MM (BB * LL)          // 16384 rows
#define LN_EPS 1e-5f
#define LDQVG 3072            // fused q|v|g row stride
#define SCC 16                // scan chunk length
#define NCHUNK (LL / SCC)     // 256 chunks per batch

typedef __hip_bfloat16 bf16;
typedef __attribute__((ext_vector_type(8))) short short8;
typedef __attribute__((ext_vector_type(16))) float float16_t;

struct bf16x4 { bf16 a, b, c, d; };
struct alignas(16) bf8 { bf16 e[8]; };

__device__ __forceinline__ float b2f(bf16 u) {
    union { unsigned int i; float f; } c;
    c.i = ((unsigned int)__bfloat16_as_ushort(u)) << 16;
    return c.f;
}

__device__ __forceinline__ float lam_of(const float* beta, int head) {
    float lam = 1.0f - exp2f(-beta[head]);
    return fminf(fmaxf(lam, 1.1754944e-38f), 1.0f - 1e-9f);
}

// ---------------------------------------------------------------------------
// All f32->bf16 conversions in ONE dispatch: x (16384 blocks) then the four
// weight matrices (4*1024 blocks) into contiguous wq|wv|wg|wo.
// ---------------------------------------------------------------------------
__global__ __launch_bounds__(256) void cvt_all(const float* __restrict__ x,
                                               const float* __restrict__ wq,
                                               const float* __restrict__ wv,
                                               const float* __restrict__ wg,
                                               const float* __restrict__ wo,
                                               bf16* __restrict__ xb,
                                               bf16* __restrict__ wb) {
    const int blk = blockIdx.x;
    const float* src;
    bf16* dst;
    size_t off;
    if (blk < 16384) {
        src = x; dst = xb; off = (size_t)blk * 1024;
    } else {
        int wblk  = blk - 16384;
        int which = wblk >> 10;
        src = (which == 0) ? wq : (which == 1) ? wv : (which == 2) ? wg : wo;
        dst = wb + (size_t)which * 1048576;
        off = (size_t)(wblk & 1023) * 1024;
    }
    size_t i = off + threadIdx.x * 4;
    float4 f = *(const float4*)(src + i);
    bf16x4 o;
    o.a = __float2bfloat16(f.x);
    o.b = __float2bfloat16(f.y);
    o.c = __float2bfloat16(f.z);
    o.d = __float2bfloat16(f.w);
    *(bf16x4*)(dst + i) = o;
}

// ---------------------------------------------------------------------------
// async 16B global -> LDS. NOTE: imm offset applies to BOTH global and LDS
// addresses — always pass 0, advance global pointers manually.
// ---------------------------------------------------------------------------
__device__ __forceinline__ void async16(const bf16* g, bf16* l) {
    __builtin_amdgcn_global_load_lds(
        (const __attribute__((address_space(1))) void*)g,
        (__attribute__((address_space(3))) void*)l,
        16, 0, 0);
}

// ---------------------------------------------------------------------------
// GEMM: C[M,N] = A[M,K] * B[N,K]^T  (row-major, K contiguous), ldc row stride.
//
// R3 structure: 256x128 block tile, 256 threads = 4 waves (2M x 2N), each
// wave 128x64 output = 4x2 of v_mfma_f32_32x32x16_bf16 (128 f32 acc/lane).
//  - LDS ring-3 of BK=32 slots: A 16KB + B 8KB per slot = 72KB total
//    -> TWO blocks/CU (144KB <= 160KB). Cross-block overlap (m114) hides
//    the LDS-read <-> MFMA serialization that capped the 1-block/CU 256^2
//    structure at 32% MfmaUtil (R2 post-mortem).
//  - ONE raw s_barrier per K-tile. Hazard audit: stage of tile T+2 targets
//    slot (T+2)%3 = slot(T-1), whose reads completed before MFMA(T-1)'s
//    implicit lgkmcnt wait, which precedes barrier(T-1), which precedes any
//    wave's tile-T stage. Stage completion before read: vmcnt(6) at tile end
//    retires tile T+1's 6 loads (per wave), then the barrier publishes them.
//  - counted vmcnt(6) in steady state (2 tiles / 12 loads in flight);
//    epilogue drains 6 -> 0. Never a full drain mid-loop.
//  - LDS swizzle (R1-verified, zero conflicts): phys 16B-chunk =
//    logical ^ ((row>>1)&3); row stride 64B. For a 32x32 fragment read
//    (row = lane&31, chunk = 2kk + (lane>>5)) the 64 lanes hit each 16B
//    slot of the 128B bank span exactly 8 times = the bandwidth floor.
//    Applied as pre-swizzled GLOBAL source + linear LDS dest + swizzled
//    ds_read address (both-sides involution).
// ---------------------------------------------------------------------------
template <typename OutT, int KK>
__global__ __launch_bounds__(256, 2) void gemm_ring(const bf16* __restrict__ A,
                                                    const bf16* __restrict__ Bm,
                                                    OutT* __restrict__ C,
                                                    int ldc) {
    constexpr int BK    = 32;
    constexpr int NT    = KK / BK;        // 32 K-tiles
    constexpr int ASLOT = 256 * BK;       // 8192 elems = 16 KB
    constexpr int BSLOT = 128 * BK;       // 4096 elems =  8 KB

    __shared__ alignas(16) bf16 sA[3 * ASLOT];   // 48 KB
    __shared__ alignas(16) bf16 sB[3 * BSLOT];   // 24 KB

    const int t    = threadIdx.x;
    const int lane = t & 63;
    const int wave = t >> 6;
    const int wm   = wave >> 1;          // 0..1 (M half: 128 rows)
    const int wn   = wave & 1;           // 0..1 (N half: 64 cols)
    const int bm   = blockIdx.x;
    const int bn   = blockIdx.y;

    // ---- staging: thread t owns phys chunk t&3 of row t>>2 (+j*64 rows).
    // phys chunk p at row r holds logical chunk p ^ ((r>>1)&3); +64 rows
    // preserves (r>>1)&3, so one cswz serves all j.
    const int srow = t >> 2;
    const int cswz = ((t & 3) ^ ((srow >> 1) & 3)) * 8;
    const bf16* gA = A  + (size_t)(bm * 256 + srow) * KK + cswz;
    const bf16* gB = Bm + (size_t)(bn * 128 + srow) * KK + cswz;
    const size_t rstep = (size_t)64 * KK;        // +64 rows
    bf16* const lA = sA + t * 8;
    bf16* const lB = sB + t * 8;

    // ---- ds_read addresses (loop-invariant, slot offset added at use).
    // 32x32x16 A/B frag: row = base + (lane&31), logical chunk = 2kk+(lane>>5).
    const int kh = lane >> 5;
    const int f  = ((lane & 31) >> 1) & 3;
    const bf16* rdA[4][2];
    const bf16* rdB[2][2];
#pragma unroll
    for (int mi = 0; mi < 4; ++mi)
#pragma unroll
        for (int kk = 0; kk < 2; ++kk) {
            const int row = wm * 128 + mi * 32 + (lane & 31);
            rdA[mi][kk] = sA + row * BK + (((2 * kk + kh) ^ f) * 8);
        }
#pragma unroll
    for (int ni = 0; ni < 2; ++ni)
#pragma unroll
        for (int kk = 0; kk < 2; ++kk) {
            const int row = wn * 64 + ni * 32 + (lane & 31);
            rdB[ni][kk] = sB + row * BK + (((2 * kk + kh) ^ f) * 8);
        }

    float16_t acc[4][2] = {};

    // slot element-offsets: slR = slot(T), slS = slot(T+2) (rotate mod 3)
    int slR = 0,         slR2 = 0;
    int slS = 2 * ASLOT, slS2 = 2 * BSLOT;

    // ---- prologue: stage tiles 0,1; wait tile 0 (vmcnt 12->6); publish.
#pragma unroll
    for (int j = 0; j < 4; ++j) async16(gA + j * rstep, lA + j * 2048);
#pragma unroll
    for (int j = 0; j < 2; ++j) async16(gB + j * rstep, lB + j * 2048);
    gA += BK; gB += BK;
#pragma unroll
    for (int j = 0; j < 4; ++j) async16(gA + j * rstep, lA + ASLOT + j * 2048);
#pragma unroll
    for (int j = 0; j < 2; ++j) async16(gB + j * rstep, lB + BSLOT + j * 2048);
    gA += BK; gB += BK;
    asm volatile("s_waitcnt vmcnt(6)" ::: "memory");
    __builtin_amdgcn_s_barrier();

#define TILE(DOSTAGE, VMN)                                                     \
  {                                                                            \
    short8 a[4][2], b[2][2];                                                   \
    _Pragma("unroll") for (int mi = 0; mi < 4; ++mi)                           \
      _Pragma("unroll") for (int kk = 0; kk < 2; ++kk)                         \
        a[mi][kk] = *(const short8*)(rdA[mi][kk] + slR);                       \
    _Pragma("unroll") for (int ni = 0; ni < 2; ++ni)                           \
      _Pragma("unroll") for (int kk = 0; kk < 2; ++kk)                         \
        b[ni][kk] = *(const short8*)(rdB[ni][kk] + slR2);                      \
    if (DOSTAGE) {                                                             \
      _Pragma("unroll") for (int j = 0; j < 4; ++j)                            \
          async16(gA + j * rstep, lA + slS + j * 2048);                        \
      _Pragma("unroll") for (int j = 0; j < 2; ++j)                            \
          async16(gB + j * rstep, lB + slS2 + j * 2048);                       \
      gA += BK; gB += BK;                                                      \
    }                                                                          \
    __builtin_amdgcn_s_setprio(1);                                             \
    _Pragma("unroll") for (int kk = 0; kk < 2; ++kk)                           \
      _Pragma("unroll") for (int mi = 0; mi < 4; ++mi)                         \
        _Pragma("unroll") for (int ni = 0; ni < 2; ++ni)                       \
          acc[mi][ni] = __builtin_amdgcn_mfma_f32_32x32x16_bf16(               \
              a[mi][kk], b[ni][kk], acc[mi][ni], 0, 0, 0);                     \
    __builtin_amdgcn_s_setprio(0);                                             \
    if ((VMN) == 6)      asm volatile("s_waitcnt vmcnt(6)" ::: "memory");      \
    else if ((VMN) == 0) asm volatile("s_waitcnt vmcnt(0)" ::: "memory");      \
    if ((VMN) >= 0) __builtin_amdgcn_s_barrier();                              \
    slR  = (slR  == 2 * ASLOT) ? 0 : slR  + ASLOT;                             \
    slR2 = (slR2 == 2 * BSLOT) ? 0 : slR2 + BSLOT;                             \
    slS  = (slS  == 2 * ASLOT) ? 0 : slS  + ASLOT;                             \
    slS2 = (slS2 == 2 * BSLOT) ? 0 : slS2 + BSLOT;                             \
  }

    // main loop: T = 0..NT-3 stage tiles 2..NT-1, counted vmcnt(6)
#pragma unroll 1
    for (int T = 0; T < NT - 2; ++T) {
        TILE(true, 6);
    }
    TILE(false, 0);    // T = NT-2: drain tile NT-1's loads
    TILE(false, -1);   // T = NT-1: no sync, fall through to epilogue

#undef TILE

    // epilogue: 32x32 C/D layout: col=lane&31, row=(reg&3)+8*(reg>>2)+4*(lane>>5)
    const int col0 = bn * 128 + wn * 64 + (lane & 31);
    const int row0 = bm * 256 + wm * 128 + 4 * (lane >> 5);
#pragma unroll
    for (int mi = 0; mi < 4; ++mi) {
#pragma unroll
        for (int ni = 0; ni < 2; ++ni) {
#pragma unroll
            for (int reg = 0; reg < 16; ++reg) {
                int row = row0 + mi * 32 + (reg & 3) + 8 * (reg >> 2);
                C[(size_t)row * ldc + col0 + ni * 32] = (OutT)acc[mi][ni][reg];
            }
        }
    }
}

// ---------------------------------------------------------------------------
// Exact two-phase retention scan over fused qvg layout (row stride 3072).
// Phase A: per-chunk local scan -> chunk sums S.
// Phase B: carry scan over chunks (8-wide prefetch pipeline).
// Phase C (fused with LN+gate below): re-scan from carry, LN, gate, write z.
// ---------------------------------------------------------------------------
__global__ __launch_bounds__(64) void scan_chunksum(const bf16* __restrict__ qvg,
                                                    const float* __restrict__ beta,
                                                    float* __restrict__ S) {
    const int c    = blockIdx.x;
    const int half = blockIdx.y;
    const int b    = blockIdx.z;
    const int tid  = threadIdx.x;
    const int dh0  = half * 512 + tid * 8;
    const float lam = lam_of(beta, dh0 >> 6);

    const bf16* vp = qvg + 1024 + ((size_t)(b * LL + c * SCC)) * LDQVG + dh0;

    float s[8] = {};
#pragma unroll
    for (int t = 0; t < SCC; ++t) {
        bf8 vv = *(const bf8*)(vp + (size_t)t * LDQVG);
#pragma unroll
        for (int j = 0; j < 8; ++j)
            s[j] = fmaf(s[j], lam, b2f(vv.e[j]));
    }

    float* sp = S + ((size_t)(b * NCHUNK + c)) * DD + dh0;
    float4 lo = {s[0], s[1], s[2], s[3]};
    float4 hi = {s[4], s[5], s[6], s[7]};
    *(float4*)(sp)     = lo;
    *(float4*)(sp + 4) = hi;
}

// Serial carry over 256 chunks, 8-wide load prefetch to break the
// latency chain (loads for batch i+1 are independent of the t-recurrence).
__global__ __launch_bounds__(64) void scan_carry(const float* __restrict__ S,
                                                 float* __restrict__ T,
                                                 const float* __restrict__ beta) {
    const int gid = blockIdx.x * 64 + threadIdx.x;  // 0..4095
    const int b = gid >> 10;
    const int f = gid & 1023;
    const float lam  = lam_of(beta, f >> 6);
    const float lamC = powf(lam, (float)SCC);

    const size_t base = (size_t)b * NCHUNK * DD + f;

    float v[8];
#pragma unroll
    for (int j = 0; j < 8; ++j) v[j] = S[base + (size_t)j * DD];

    float t = 0.0f;
    for (int c0 = 0; c0 < NCHUNK; c0 += 8) {
        float cur[8];
#pragma unroll
        for (int j = 0; j < 8; ++j) cur[j] = v[j];
        if (c0 + 8 < NCHUNK) {
#pragma unroll
            for (int j = 0; j < 8; ++j)
                v[j] = S[base + (size_t)(c0 + 8 + j) * DD];
        }
#pragma unroll
        for (int j = 0; j < 8; ++j) {
            T[base + (size_t)(c0 + j) * DD] = t;
            t = fmaf(t, lamC, cur[j]);
        }
    }
}

// ---------------------------------------------------------------------------
// Fused: re-scan chunk from carry T -> ret (kept in LDS), per-row LayerNorm,
// SiLU gate, write z (bf16, contiguous [M,1024]). ret never touches HBM.
// grid (NCHUNK, BB), 128 threads (2 waves). LDS 16 rows x 1024 bf16 = 32KB.
// ---------------------------------------------------------------------------
__global__ __launch_bounds__(128) void scan_apply_ln(const bf16* __restrict__ qvg,
                                                     const float* __restrict__ beta,
                                                     const float* __restrict__ T,
                                                     const float* __restrict__ gamma,
                                                     const float* __restrict__ betaln,
                                                     bf16* __restrict__ z) {
    __shared__ bf16 lds_ret[SCC][DD];   // 32 KB

    const int c   = blockIdx.x;
    const int b   = blockIdx.y;
    const int tid = threadIdx.x;        // 0..127
    const int f0  = tid * 8;
    const float lam = lam_of(beta, f0 >> 6);

    // ---- phase 1: local scan from carry, ret -> LDS ----
    const float* tp = T + ((size_t)(b * NCHUNK + c)) * DD + f0;
    float4 lo = *(const float4*)(tp);
    float4 hi = *(const float4*)(tp + 4);
    float s[8] = {lo.x, lo.y, lo.z, lo.w, hi.x, hi.y, hi.z, hi.w};

    const bf16* qp = qvg + ((size_t)(b * LL + c * SCC)) * LDQVG + f0;
#pragma unroll
    for (int t = 0; t < SCC; ++t) {
        const size_t off = (size_t)t * LDQVG;
        bf8 vv = *(const bf8*)(qp + 1024 + off);
        bf8 qq = *(const bf8*)(qp + off);
        bf8 o;
#pragma unroll
        for (int j = 0; j < 8; ++j) {
            s[j] = fmaf(s[j], lam, b2f(vv.e[j]));
            o.e[j] = __float2bfloat16(b2f(qq.e[j]) * s[j]);
        }
        *(bf8*)(&lds_ret[t][f0]) = o;
    }
    __syncthreads();

    // ---- phase 2: per-row LN + SiLU gate. wave w does rows w, w+2, ... ----
    const int lane = tid & 63;
    const int wv   = tid >> 6;

    // cache gamma/beta for this lane's two feature groups (lane*8, 512+lane*8)
    float gmA[8], btA[8], gmB[8], btB[8];
#pragma unroll
    for (int j = 0; j < 8; j += 4) {
        *(float4*)(gmA + j) = *(const float4*)(gamma  + lane * 8 + j);
        *(float4*)(btA + j) = *(const float4*)(betaln + lane * 8 + j);
        *(float4*)(gmB + j) = *(const float4*)(gamma  + 512 + lane * 8 + j);
        *(float4*)(btB + j) = *(const float4*)(betaln + 512 + lane * 8 + j);
    }

    for (int t = wv; t < SCC; t += 2) {
        bf8 rA = *(const bf8*)(&lds_ret[t][lane * 8]);
        bf8 rB = *(const bf8*)(&lds_ret[t][512 + lane * 8]);

        float xa[8], xb2[8];
        float sum = 0.f, sq = 0.f;
#pragma unroll
        for (int j = 0; j < 8; ++j) {
            xa[j]  = b2f(rA.e[j]);
            xb2[j] = b2f(rB.e[j]);
            sum += xa[j] + xb2[j];
            sq  += xa[j] * xa[j] + xb2[j] * xb2[j];
        }
#pragma unroll
        for (int off = 32; off >= 1; off >>= 1) {
            sum += __shfl_xor(sum, off, 64);
            sq  += __shfl_xor(sq,  off, 64);
        }
        const float mu   = sum * (1.0f / DD);
        const float var  = sq * (1.0f / DD) - mu * mu;
        const float rstd = rsqrtf(var + LN_EPS);

        const size_t row = (size_t)(b * LL + c * SCC + t);
        const bf16* gp = qvg + row * LDQVG + 2048 + lane * 8;
        bf8 gA = *(const bf8*)(gp);
        bf8 gB = *(const bf8*)(gp + 512);

        bf8 oA, oB;
#pragma unroll
        for (int j = 0; j < 8; ++j) {
            float ya = (xa[j]  - mu) * rstd * gmA[j] + btA[j];
            float yb = (xb2[j] - mu) * rstd * gmB[j] + btB[j];
            float ga = b2f(gA.e[j]);
            float gb = b2f(gB.e[j]);
            oA.e[j] = __float2bfloat16(ya * (ga / (1.0f + expf(-ga))));
            oB.e[j] = __float2bfloat16(yb * (gb / (1.0f + expf(-gb))));
        }
        bf16* zp = z + row * DD + lane * 8;
        *(bf8*)(zp)       = oA;
        *(bf8*)(zp + 512) = oB;
    }
}

// ---------------------------------------------------------------------------
// launch
// ---------------------------------------------------------------------------
extern "C" void kernel_launch(void* const* d_in, const int* in_sizes, int n_in,
                              void* d_out, int out_size, void* d_ws, size_t ws_size,
                              hipStream_t stream) {
    const float* x     = (const float*)d_in[0];
    const float* Wq    = (const float*)d_in[1];
    const float* Wv    = (const float*)d_in[2];
    const float* Wo    = (const float*)d_in[3];
    const float* Wg    = (const float*)d_in[4];
    const float* beta  = (const float*)d_in[5];
    const float* ln_g  = (const float*)d_in[6];
    const float* ln_b  = (const float*)d_in[7];
    float* out = (float*)d_out;

    char* ws = (char*)d_ws;
    // workspace (136MB total, time-multiplexed):
    //   @0    : xb 32MB (cvt -> QVG GEMM)  ->  S 4MB (chunksum -> carry)
    //           -> zb 32MB (apply_ln -> final GEMM)
    //   @32MB : wqb 6MB (wq|wv|wg; dead after QVG GEMM) -> T 4MB (carry -> apply)
    //   @38MB : wob 2MB (live until final GEMM)
    //   @40MB : qvg 96MB [M,3072] = q|v|g per row
    bf16*  xb   = (bf16*)ws;
    float* Sbuf = (float*)ws;                                  // alias xb (dead)
    bf16*  wqb  = (bf16*)(ws + (size_t)32 * 1024 * 1024);
    float* Tbuf = (float*)(ws + (size_t)32 * 1024 * 1024);     // alias wqb (dead)
    bf16*  wob  = wqb + 3 * 1048576;
    bf16*  qvg  = (bf16*)(ws + (size_t)40 * 1024 * 1024);
    bf16*  zb   = xb;

    // all dtype conversions in one dispatch (x + 4 weights)
    cvt_all<<<dim3(16384 + 4096), dim3(256), 0, stream>>>(x, Wq, Wv, Wg, Wo, xb, wqb);

    // fused QVG GEMM: [M,1024] x [3072,1024]^T -> [M,3072]
    gemm_ring<bf16, DD><<<dim3(MM / 256, LDQVG / 128), dim3(256), 0, stream>>>(
        xb, wqb, qvg, LDQVG);

    // exact two-phase retention scan + fused LN/gate
    scan_chunksum<<<dim3(NCHUNK, 2, BB), dim3(64), 0, stream>>>(qvg, beta, Sbuf);
    scan_carry<<<dim3(64), dim3(64), 0, stream>>>(Sbuf, Tbuf, beta);
    scan_apply_ln<<<dim3(NCHUNK, BB), dim3(128), 0, stream>>>(
        qvg, beta, Tbuf, ln_g, ln_b, zb);

    // final GEMM: [M,1024] x [1024,1024]^T -> [M,1024] f32
    gemm_ring<float, DD><<<dim3(MM / 256, DD / 128), dim3(256), 0, stream>>>(
        zb, wob, out, DD);
}

// Round 4
// 333.312 us; speedup vs baseline: 1.0877x; 1.0452x over previous
//
#include <hip/hip_runtime.h>
#include <hip/hip_bf16.h>
#include <cfloat>

// Problem constants (reference: B=4, L=4096, D=1024, H=16, Dh=64)
#define BB 4
#define LL 4096
#define DD 1024
#define HH 16
#define DHH 64
#define MM (BB * LL)          // 16384 rows
#define LN_EPS 1e-5f
#define LDQVG 3072            // fused q|v|g row stride
#define SCC 16                // scan chunk length
#define NCHUNK (LL / SCC)     // 256 chunks per batch

typedef __hip_bfloat16 bf16;
typedef __attribute__((ext_vector_type(8))) short short8;
typedef __attribute__((ext_vector_type(4))) float f32x4;

struct bf16x4 { bf16 a, b, c, d; };
struct alignas(16) bf8 { bf16 e[8]; };

__device__ __forceinline__ float b2f(bf16 u) {
    union { unsigned int i; float f; } c;
    c.i = ((unsigned int)__bfloat16_as_ushort(u)) << 16;
    return c.f;
}

__device__ __forceinline__ float lam_of(const float* beta, int head) {
    float lam = 1.0f - exp2f(-beta[head]);
    return fminf(fmaxf(lam, 1.1754944e-38f), 1.0f - 1e-9f);
}

// ---------------------------------------------------------------------------
// All f32->bf16 conversions in ONE dispatch: x (16384 blocks) then the four
// weight matrices (4*1024 blocks) into contiguous wq|wv|wg|wo.
// ---------------------------------------------------------------------------
__global__ __launch_bounds__(256) void cvt_all(const float* __restrict__ x,
                                               const float* __restrict__ wq,
                                               const float* __restrict__ wv,
                                               const float* __restrict__ wg,
                                               const float* __restrict__ wo,
                                               bf16* __restrict__ xb,
                                               bf16* __restrict__ wb) {
    const int blk = blockIdx.x;
    const float* src;
    bf16* dst;
    size_t off;
    if (blk < 16384) {
        src = x; dst = xb; off = (size_t)blk * 1024;
    } else {
        int wblk  = blk - 16384;
        int which = wblk >> 10;
        src = (which == 0) ? wq : (which == 1) ? wv : (which == 2) ? wg : wo;
        dst = wb + (size_t)which * 1048576;
        off = (size_t)(wblk & 1023) * 1024;
    }
    size_t i = off + threadIdx.x * 4;
    float4 f = *(const float4*)(src + i);
    bf16x4 o;
    o.a = __float2bfloat16(f.x);
    o.b = __float2bfloat16(f.y);
    o.c = __float2bfloat16(f.z);
    o.d = __float2bfloat16(f.w);
    *(bf16x4*)(dst + i) = o;
}

// ---------------------------------------------------------------------------
// async 16B global -> LDS. NOTE: imm offset applies to BOTH global and LDS
// addresses — always pass 0, advance global pointers manually.
// ---------------------------------------------------------------------------
__device__ __forceinline__ void async16(const bf16* g, bf16* l) {
    __builtin_amdgcn_global_load_lds(
        (const __attribute__((address_space(1))) void*)g,
        (__attribute__((address_space(3))) void*)l,
        16, 0, 0);
}

// ---------------------------------------------------------------------------
// GEMM: C[M,N] = A[M,K] * B[N,K]^T  (row-major, K contiguous), ldc row stride.
//
// R4 structure: 256x128 block tile, 256 threads = 4 waves (2M x 2N), each
// wave 128x64 output = 8x4 of v_mfma_f32_16x16x32_bf16 (acc[8][4] f32x4 =
// 128 f32/lane).
//  - LDS ring-3 of BK=32 slots: A 16KB + B 8KB per slot = 72KB total
//    -> TWO blocks/CU (144KB <= 160KB) for cross-block overlap (m114).
//  - ONE raw s_barrier per K-tile; counted vmcnt(6) steady state (2 tiles /
//    12 loads in flight); epilogue drains 6 -> 0.
//    Hazard audit: stage of tile T+2 targets slot (T+2)%3 = slot(T-1), whose
//    reads completed (lgkm) before MFMA(T-1), before barrier(T-1), before
//    any wave's tile-T stage. vmcnt(6) at tile end retires tile T+1's loads,
//    then the barrier publishes them.
//  - LDS swizzle: phys 16B-chunk = logical ^ ((row>>1)&3), 64B rows.
//    R3 post-mortem: this involution is conflict-free ONLY for the 16x16
//    read pattern (row = mult16 + (lane&15), chunk = lane>>4) — measured 0
//    in R1. The 32x32 pattern (row = lane&31) measured exactly +4 cyc per
//    ds_read_b128 (9437184 = 4.0 x reads, both R0 and R3). So R4 keeps the
//    staging bytes IDENTICAL to R3 and reads with 16x16 fragments.
//    Applied as pre-swizzled GLOBAL source + linear LDS dest + swizzled
//    ds_read address (both-sides involution).
// ---------------------------------------------------------------------------
template <typename OutT, int KK>
__global__ __launch_bounds__(256, 2) void gemm_ring(const bf16* __restrict__ A,
                                                    const bf16* __restrict__ Bm,
                                                    OutT* __restrict__ C,
                                                    int ldc) {
    constexpr int BK    = 32;
    constexpr int NT    = KK / BK;        // 32 K-tiles
    constexpr int ASLOT = 256 * BK;       // 8192 elems = 16 KB
    constexpr int BSLOT = 128 * BK;       // 4096 elems =  8 KB

    __shared__ alignas(16) bf16 sA[3 * ASLOT];   // 48 KB
    __shared__ alignas(16) bf16 sB[3 * BSLOT];   // 24 KB

    const int t    = threadIdx.x;
    const int lane = t & 63;
    const int wave = t >> 6;
    const int wm   = wave >> 1;          // 0..1 (M half: 128 rows)
    const int wn   = wave & 1;           // 0..1 (N half: 64 cols)
    const int bm   = blockIdx.x;
    const int bn   = blockIdx.y;

    // ---- staging: thread t owns phys chunk t&3 of row t>>2 (+j*64 rows).
    // phys chunk p at row r holds logical chunk p ^ ((r>>1)&3); +64 rows
    // preserves (r>>1)&3, so one cswz serves all j. (Identical to R3.)
    const int srow = t >> 2;
    const int cswz = ((t & 3) ^ ((srow >> 1) & 3)) * 8;
    const bf16* gA = A  + (size_t)(bm * 256 + srow) * KK + cswz;
    const bf16* gB = Bm + (size_t)(bn * 128 + srow) * KK + cswz;
    const size_t rstep = (size_t)64 * KK;        // +64 rows
    bf16* const lA = sA + t * 8;
    bf16* const lB = sB + t * 8;

    // ---- ds_read addressing (R1-verified ZERO-conflict pattern):
    // 16x16x32 frag: row = base16 + (lane&15), logical chunk = lane>>4,
    // phys = logical ^ ((row>>1)&3) = logical ^ (((lane&15)>>1)&3).
    const int f16  = lane & 15;
    const int swz8 = ((lane >> 4) ^ ((f16 >> 1) & 3)) * 8;
    const bf16* const rdA0 = sA + (wm * 128 + f16) * BK + swz8;  // +mi*512
    const bf16* const rdB0 = sB + (wn * 64  + f16) * BK + swz8;  // +ni*512

    f32x4 acc[8][4] = {};

    // slot element-offsets: slR = slot(T), slS = slot(T+2) (rotate mod 3)
    int slR = 0,         slR2 = 0;
    int slS = 2 * ASLOT, slS2 = 2 * BSLOT;

    // ---- prologue: stage tiles 0,1; wait tile 0 (vmcnt 12->6); publish.
#pragma unroll
    for (int j = 0; j < 4; ++j) async16(gA + j * rstep, lA + j * 2048);
#pragma unroll
    for (int j = 0; j < 2; ++j) async16(gB + j * rstep, lB + j * 2048);
    gA += BK; gB += BK;
#pragma unroll
    for (int j = 0; j < 4; ++j) async16(gA + j * rstep, lA + ASLOT + j * 2048);
#pragma unroll
    for (int j = 0; j < 2; ++j) async16(gB + j * rstep, lB + BSLOT + j * 2048);
    gA += BK; gB += BK;
    asm volatile("s_waitcnt vmcnt(6)" ::: "memory");
    __builtin_amdgcn_s_barrier();

#define TILE(DOSTAGE, VMN)                                                     \
  {                                                                            \
    short8 a[8], b[4];                                                         \
    a[0] = *(const short8*)(rdA0 + slR);                                       \
    _Pragma("unroll") for (int ni = 0; ni < 4; ++ni)                           \
        b[ni] = *(const short8*)(rdB0 + ni * 512 + slR2);                      \
    _Pragma("unroll") for (int mi = 1; mi < 8; ++mi)                           \
        a[mi] = *(const short8*)(rdA0 + mi * 512 + slR);                       \
    if (DOSTAGE) {                                                             \
      _Pragma("unroll") for (int j = 0; j < 4; ++j)                            \
          async16(gA + j * rstep, lA + slS + j * 2048);                        \
      _Pragma("unroll") for (int j = 0; j < 2; ++j)                            \
          async16(gB + j * rstep, lB + slS2 + j * 2048);                       \
      gA += BK; gB += BK;                                                      \
    }                                                                          \
    __builtin_amdgcn_s_setprio(1);                                             \
    _Pragma("unroll") for (int mi = 0; mi < 8; ++mi)                           \
      _Pragma("unroll") for (int ni = 0; ni < 4; ++ni)                         \
        acc[mi][ni] = __builtin_amdgcn_mfma_f32_16x16x32_bf16(                 \
            a[mi], b[ni], acc[mi][ni], 0, 0, 0);                               \
    __builtin_amdgcn_s_setprio(0);                                             \
    if ((VMN) == 6)      asm volatile("s_waitcnt vmcnt(6)" ::: "memory");      \
    else if ((VMN) == 0) asm volatile("s_waitcnt vmcnt(0)" ::: "memory");      \
    if ((VMN) >= 0) __builtin_amdgcn_s_barrier();                              \
    slR  = (slR  == 2 * ASLOT) ? 0 : slR  + ASLOT;                             \
    slR2 = (slR2 == 2 * BSLOT) ? 0 : slR2 + BSLOT;                             \
    slS  = (slS  == 2 * ASLOT) ? 0 : slS  + ASLOT;                             \
    slS2 = (slS2 == 2 * BSLOT) ? 0 : slS2 + BSLOT;                             \
  }

    // main loop: T = 0..NT-3 stage tiles 2..NT-1, counted vmcnt(6)
#pragma unroll 1
    for (int T = 0; T < NT - 2; ++T) {
        TILE(true, 6);
    }
    TILE(false, 0);    // T = NT-2: drain tile NT-1's loads
    TILE(false, -1);   // T = NT-1: no sync, fall through to epilogue

#undef TILE

    // epilogue: 16x16 C/D layout: col = lane&15, row = (lane>>4)*4 + reg
    const int col0 = bn * 128 + wn * 64 + (lane & 15);
    const int row0 = bm * 256 + wm * 128 + ((lane >> 4) * 4);
#pragma unroll
    for (int mi = 0; mi < 8; ++mi) {
#pragma unroll
        for (int ni = 0; ni < 4; ++ni) {
#pragma unroll
            for (int r = 0; r < 4; ++r) {
                int row = row0 + mi * 16 + r;
                C[(size_t)row * ldc + col0 + ni * 16] = (OutT)acc[mi][ni][r];
            }
        }
    }
}

// ---------------------------------------------------------------------------
// Exact two-phase retention scan over fused qvg layout (row stride 3072).
// Phase A: per-chunk local scan -> chunk sums S.
// Phase B: carry scan over chunks (8-wide prefetch pipeline).
// Phase C (fused with LN+gate below): re-scan from carry, LN, gate, write z.
// ---------------------------------------------------------------------------
__global__ __launch_bounds__(64) void scan_chunksum(const bf16* __restrict__ qvg,
                                                    const float* __restrict__ beta,
                                                    float* __restrict__ S) {
    const int c    = blockIdx.x;
    const int half = blockIdx.y;
    const int b    = blockIdx.z;
    const int tid  = threadIdx.x;
    const int dh0  = half * 512 + tid * 8;
    const float lam = lam_of(beta, dh0 >> 6);

    const bf16* vp = qvg + 1024 + ((size_t)(b * LL + c * SCC)) * LDQVG + dh0;

    float s[8] = {};
#pragma unroll
    for (int t = 0; t < SCC; ++t) {
        bf8 vv = *(const bf8*)(vp + (size_t)t * LDQVG);
#pragma unroll
        for (int j = 0; j < 8; ++j)
            s[j] = fmaf(s[j], lam, b2f(vv.e[j]));
    }

    float* sp = S + ((size_t)(b * NCHUNK + c)) * DD + dh0;
    float4 lo = {s[0], s[1], s[2], s[3]};
    float4 hi = {s[4], s[5], s[6], s[7]};
    *(float4*)(sp)     = lo;
    *(float4*)(sp + 4) = hi;
}

// Serial carry over 256 chunks, 8-wide load prefetch to break the
// latency chain (loads for batch i+1 are independent of the t-recurrence).
__global__ __launch_bounds__(64) void scan_carry(const float* __restrict__ S,
                                                 float* __restrict__ T,
                                                 const float* __restrict__ beta) {
    const int gid = blockIdx.x * 64 + threadIdx.x;  // 0..4095
    const int b = gid >> 10;
    const int f = gid & 1023;
    const float lam  = lam_of(beta, f >> 6);
    const float lamC = powf(lam, (float)SCC);

    const size_t base = (size_t)b * NCHUNK * DD + f;

    float v[8];
#pragma unroll
    for (int j = 0; j < 8; ++j) v[j] = S[base + (size_t)j * DD];

    float t = 0.0f;
    for (int c0 = 0; c0 < NCHUNK; c0 += 8) {
        float cur[8];
#pragma unroll
        for (int j = 0; j < 8; ++j) cur[j] = v[j];
        if (c0 + 8 < NCHUNK) {
#pragma unroll
            for (int j = 0; j < 8; ++j)
                v[j] = S[base + (size_t)(c0 + 8 + j) * DD];
        }
#pragma unroll
        for (int j = 0; j < 8; ++j) {
            T[base + (size_t)(c0 + j) * DD] = t;
            t = fmaf(t, lamC, cur[j]);
        }
    }
}

// ---------------------------------------------------------------------------
// Fused: re-scan chunk from carry T -> ret (kept in LDS), per-row LayerNorm,
// SiLU gate, write z (bf16, contiguous [M,1024]). ret never touches HBM.
// grid (NCHUNK, BB), 128 threads (2 waves). LDS 16 rows x 1024 bf16 = 32KB.
// ---------------------------------------------------------------------------
__global__ __launch_bounds__(128) void scan_apply_ln(const bf16* __restrict__ qvg,
                                                     const float* __restrict__ beta,
                                                     const float* __restrict__ T,
                                                     const float* __restrict__ gamma,
                                                     const float* __restrict__ betaln,
                                                     bf16* __restrict__ z) {
    __shared__ bf16 lds_ret[SCC][DD];   // 32 KB

    const int c   = blockIdx.x;
    const int b   = blockIdx.y;
    const int tid = threadIdx.x;        // 0..127
    const int f0  = tid * 8;
    const float lam = lam_of(beta, f0 >> 6);

    // ---- phase 1: local scan from carry, ret -> LDS ----
    const float* tp = T + ((size_t)(b * NCHUNK + c)) * DD + f0;
    float4 lo = *(const float4*)(tp);
    float4 hi = *(const float4*)(tp + 4);
    float s[8] = {lo.x, lo.y, lo.z, lo.w, hi.x, hi.y, hi.z, hi.w};

    const bf16* qp = qvg + ((size_t)(b * LL + c * SCC)) * LDQVG + f0;
#pragma unroll
    for (int t = 0; t < SCC; ++t) {
        const size_t off = (size_t)t * LDQVG;
        bf8 vv = *(const bf8*)(qp + 1024 + off);
        bf8 qq = *(const bf8*)(qp + off);
        bf8 o;
#pragma unroll
        for (int j = 0; j < 8; ++j) {
            s[j] = fmaf(s[j], lam, b2f(vv.e[j]));
            o.e[j] = __float2bfloat16(b2f(qq.e[j]) * s[j]);
        }
        *(bf8*)(&lds_ret[t][f0]) = o;
    }
    __syncthreads();

    // ---- phase 2: per-row LN + SiLU gate. wave w does rows w, w+2, ... ----
    const int lane = tid & 63;
    const int wv   = tid >> 6;

    // cache gamma/beta for this lane's two feature groups (lane*8, 512+lane*8)
    float gmA[8], btA[8], gmB[8], btB[8];
#pragma unroll
    for (int j = 0; j < 8; j += 4) {
        *(float4*)(gmA + j) = *(const float4*)(gamma  + lane * 8 + j);
        *(float4*)(btA + j) = *(const float4*)(betaln + lane * 8 + j);
        *(float4*)(gmB + j) = *(const float4*)(gamma  + 512 + lane * 8 + j);
        *(float4*)(btB + j) = *(const float4*)(betaln + 512 + lane * 8 + j);
    }

    for (int t = wv; t < SCC; t += 2) {
        bf8 rA = *(const bf8*)(&lds_ret[t][lane * 8]);
        bf8 rB = *(const bf8*)(&lds_ret[t][512 + lane * 8]);

        float xa[8], xb2[8];
        float sum = 0.f, sq = 0.f;
#pragma unroll
        for (int j = 0; j < 8; ++j) {
            xa[j]  = b2f(rA.e[j]);
            xb2[j] = b2f(rB.e[j]);
            sum += xa[j] + xb2[j];
            sq  += xa[j] * xa[j] + xb2[j] * xb2[j];
        }
#pragma unroll
        for (int off = 32; off >= 1; off >>= 1) {
            sum += __shfl_xor(sum, off, 64);
            sq  += __shfl_xor(sq,  off, 64);
        }
        const float mu   = sum * (1.0f / DD);
        const float var  = sq * (1.0f / DD) - mu * mu;
        const float rstd = rsqrtf(var + LN_EPS);

        const size_t row = (size_t)(b * LL + c * SCC + t);
        const bf16* gp = qvg + row * LDQVG + 2048 + lane * 8;
        bf8 gA = *(const bf8*)(gp);
        bf8 gB = *(const bf8*)(gp + 512);

        bf8 oA, oB;
#pragma unroll
        for (int j = 0; j < 8; ++j) {
            float ya = (xa[j]  - mu) * rstd * gmA[j] + btA[j];
            float yb = (xb2[j] - mu) * rstd * gmB[j] + btB[j];
            float ga = b2f(gA.e[j]);
            float gb = b2f(gB.e[j]);
            oA.e[j] = __float2bfloat16(ya * (ga / (1.0f + expf(-ga))));
            oB.e[j] = __float2bfloat16(yb * (gb / (1.0f + expf(-gb))));
        }
        bf16* zp = z + row * DD + lane * 8;
        *(bf8*)(zp)       = oA;
        *(bf8*)(zp + 512) = oB;
    }
}

// ---------------------------------------------------------------------------
// launch
// ---------------------------------------------------------------------------
extern "C" void kernel_launch(void* const* d_in, const int* in_sizes, int n_in,
                              void* d_out, int out_size, void* d_ws, size_t ws_size,
                              hipStream_t stream) {
    const float* x     = (const float*)d_in[0];
    const float* Wq    = (const float*)d_in[1];
    const float* Wv    = (const float*)d_in[2];
    const float* Wo    = (const float*)d_in[3];
    const float* Wg    = (const float*)d_in[4];
    const float* beta  = (const float*)d_in[5];
    const float* ln_g  = (const float*)d_in[6];
    const float* ln_b  = (const float*)d_in[7];
    float* out = (float*)d_out;

    char* ws = (char*)d_ws;
    // workspace (136MB total, time-multiplexed):
    //   @0    : xb 32MB (cvt -> QVG GEMM)  ->  S 4MB (chunksum -> carry)
    //           -> zb 32MB (apply_ln -> final GEMM)
    //   @32MB : wqb 6MB (wq|wv|wg; dead after QVG GEMM) -> T 4MB (carry -> apply)
    //   @38MB : wob 2MB (live until final GEMM)
    //   @40MB : qvg 96MB [M,3072] = q|v|g per row
    bf16*  xb   = (bf16*)ws;
    float* Sbuf = (float*)ws;                                  // alias xb (dead)
    bf16*  wqb  = (bf16*)(ws + (size_t)32 * 1024 * 1024);
    float* Tbuf = (float*)(ws + (size_t)32 * 1024 * 1024);     // alias wqb (dead)
    bf16*  wob  = wqb + 3 * 1048576;
    bf16*  qvg  = (bf16*)(ws + (size_t)40 * 1024 * 1024);
    bf16*  zb   = xb;

    // all dtype conversions in one dispatch (x + 4 weights)
    cvt_all<<<dim3(16384 + 4096), dim3(256), 0, stream>>>(x, Wq, Wv, Wg, Wo, xb, wqb);

    // fused QVG GEMM: [M,1024] x [3072,1024]^T -> [M,3072]
    gemm_ring<bf16, DD><<<dim3(MM / 256, LDQVG / 128), dim3(256), 0, stream>>>(
        xb, wqb, qvg, LDQVG);

    // exact two-phase retention scan + fused LN/gate
    scan_chunksum<<<dim3(NCHUNK, 2, BB), dim3(64), 0, stream>>>(qvg, beta, Sbuf);
    scan_carry<<<dim3(64), dim3(64), 0, stream>>>(Sbuf, Tbuf, beta);
    scan_apply_ln<<<dim3(NCHUNK, BB), dim3(128), 0, stream>>>(
        qvg, beta, Tbuf, ln_g, ln_b, zb);

    // final GEMM: [M,1024] x [1024,1024]^T -> [M,1024] f32
    gemm_ring<float, DD><<<dim3(MM / 256, DD / 128), dim3(256), 0, stream>>>(
        zb, wob, out, DD);
}